// Round 6
// baseline (461.682 us; speedup 1.0000x reference)
//
#include <hip/hip_runtime.h>
#include <stdint.h>
#include <math.h>

// (B,H,SQ,SK,D,DV) = (2,16,2048,2048,64,64)
// out = (softmax(q k^T) * 0.5) with dropout p=0.1 (jax x64 threefry key 42) @ v
// R16: split threefry OUT of the attention loop. R15 post-mortem: attn is
// phase-locked (barrier/iter) at ~40% true VALU issue; threefry = 90% of its
// VALU. New mask_kernel computes all 2^27 draws as pure independent ALU
// (no LDS/barriers/MFMA, 32 waves/CU) and ballot-packs keep-bits into a
// 16 MB u64 mask in ws: word[row*32+kt] bit j = keep(row, kt*64+j),
// row = global flat (b,h,q). attn_main consumes it as one uint2/iter +
// 3 bitops/element. Mask convention (verified bit-exact R13):
// bits64(i) = (o0<<32)|o1 of threefry((0,42),(0,i)), keep iff
// bits64 < 0xE666666666667000 (exact u64 form of uniform_f64 < 0.9).
// ws: Kh (4MB) | Kl (4MB) | Vt (4MB) | mask (16MB) = 28 MB.
namespace {
constexpr int Bb = 2, Hh = 16, SQc = 2048, SKc = 2048, Dc = 64, DVc = 64;
constexpr int TK = 64;
constexpr float LOG2E = 1.4426950408889634f;
constexpr uint64_t KEEP_T = 0xE666666666667000ull;  // 0.9_f64 threshold, exact

typedef __attribute__((ext_vector_type(8))) short short8;   // MFMA A/B frag (8 bf16)
typedef __attribute__((ext_vector_type(4))) float f32x4;    // MFMA C/D frag

__device__ __forceinline__ uint32_t rotl_(uint32_t x, int r) {
  return __builtin_amdgcn_alignbit(x, x, 32 - r);  // 1-instr rotate
}

// threefry2x32, key=(0,42), counter=(0, i): returns (o0 << 32) | o1.
// Injection adds fused with the following round's x0-add (v_add3_u32); mod-2^32
// associativity keeps it bit-exact vs the textbook form. VERIFIED R13.
__device__ __forceinline__ uint64_t tf_bits64(uint32_t ctr) {
  const uint32_t KS1 = 42u, KS2 = 0x1BD11BF0u;  // 0x1BD11BDA ^ 42
  uint32_t x0, x1;
  x1 = ctr + KS1;
  // group 1 (rot 13,15,26,6); x0 starts at 0 so first add folds
  x0 = x1;        x1 = rotl_(x1, 13); x1 ^= x0;
  x0 += x1;       x1 = rotl_(x1, 15); x1 ^= x0;
  x0 += x1;       x1 = rotl_(x1, 26); x1 ^= x0;
  x0 += x1;       x1 = rotl_(x1,  6); x1 ^= x0;
  // inject (KS1, KS2+1), fused
  x1 += KS2 + 1u;
  x0 += KS1 + x1; x1 = rotl_(x1, 17); x1 ^= x0;
  x0 += x1;       x1 = rotl_(x1, 29); x1 ^= x0;
  x0 += x1;       x1 = rotl_(x1, 16); x1 ^= x0;
  x0 += x1;       x1 = rotl_(x1, 24); x1 ^= x0;
  // inject (KS2, 0+2), fused
  x1 += 2u;
  x0 += KS2 + x1; x1 = rotl_(x1, 13); x1 ^= x0;
  x0 += x1;       x1 = rotl_(x1, 15); x1 ^= x0;
  x0 += x1;       x1 = rotl_(x1, 26); x1 ^= x0;
  x0 += x1;       x1 = rotl_(x1,  6); x1 ^= x0;
  // inject (0, KS1+3)
  x1 += KS1 + 3u;
  x0 += x1;       x1 = rotl_(x1, 17); x1 ^= x0;
  x0 += x1;       x1 = rotl_(x1, 29); x1 ^= x0;
  x0 += x1;       x1 = rotl_(x1, 16); x1 ^= x0;
  x0 += x1;       x1 = rotl_(x1, 24); x1 ^= x0;
  // inject (KS1, KS2+4), fused
  x1 += KS2 + 4u;
  x0 += KS1 + x1; x1 = rotl_(x1, 13); x1 ^= x0;
  x0 += x1;       x1 = rotl_(x1, 15); x1 ^= x0;
  x0 += x1;       x1 = rotl_(x1, 26); x1 ^= x0;
  x0 += x1;       x1 = rotl_(x1,  6); x1 ^= x0;
  // final inject (KS2, 0+5); o0 is the HIGH word (jax 64-bit combine)
  return ((uint64_t)(x0 + KS2) << 32) | (uint64_t)(x1 + 5u);
}

__device__ __forceinline__ uint32_t f2bf_u(float x) {  // RNE bf16 (finite x), low 16 bits
  uint32_t u = __float_as_uint(x);
  u += 0x7FFFu + ((u >> 16) & 1u);
  return u >> 16;
}

// async global->LDS, 16 B per lane; LDS base wave-uniform, global addr per-lane
__device__ __forceinline__ void gl_lds16(const void* g, void* l) {
  __builtin_amdgcn_global_load_lds(
      (const __attribute__((address_space(1))) unsigned int*)g,
      (__attribute__((address_space(3))) unsigned int*)l, 16, 0, 0);
}
}  // namespace

// Dropout mask pre-pass: pure ALU, 32 waves/CU. Wave wv handles words
// [wv*256, wv*256+256); word w covers elements w*64 + lane. One tf_bits64
// per lane per word, ballot-packed (bit = lane), lane 0 stores the u64.
__global__ __launch_bounds__(256, 8) void mask_kernel(
    unsigned long long* __restrict__ Mg) {
  const int lane = threadIdx.x & 63;
  const uint32_t wv = blockIdx.x * 4u + (threadIdx.x >> 6);  // 8192 waves
  uint32_t ctr = wv * (256u * 64u) + (uint32_t)lane;
  unsigned long long* op = Mg + (size_t)wv * 256;
#pragma unroll 2
  for (int j = 0; j < 256; ++j) {
    uint64_t bits = tf_bits64(ctr + (uint32_t)(j * 64));
    unsigned long long m = __ballot(bits < KEEP_T);
    if (lane == 0) op[j] = m;
  }
}

// Pre-pass: tile-contiguous, XOR-swizzled layouts.
// Kh/Kl tile (h,kt): shorts[4096]; elem (row,col): row*64 + ((col>>3)^(row&7))*8 + (col&7)
// Vt tile  (h,kt): shorts[4096]; elem (dv,skl) = V[kt*64+skl][dv], same swizzle on skl.
__global__ __launch_bounds__(256) void prep_kernel(
    const float* __restrict__ k, const float* __restrict__ v,
    unsigned short* __restrict__ Khg, unsigned short* __restrict__ Klg,
    unsigned short* __restrict__ Vtg) {
  __shared__ float Vs[64 * 65];
  const int t = threadIdx.x;
  const int h = blockIdx.x >> 5;
  const int kt = blockIdx.x & 31;
  const size_t src = ((size_t)h * SKc + kt * 64) * Dc;
  const size_t tb = (size_t)(h * 32 + kt) * 4096;  // tile base (shorts)
#pragma unroll
  for (int i = 0; i < 4; ++i) {
    int idx = t + 256 * i;
    int row = idx >> 4, d0 = (idx & 15) << 2;
    float4 kv = *(const float4*)(k + src + row * Dc + d0);
    uint32_t hx = f2bf_u(kv.x), hy = f2bf_u(kv.y), hz = f2bf_u(kv.z), hw = f2bf_u(kv.w);
    uint32_t lx = f2bf_u(kv.x - __uint_as_float(hx << 16));
    uint32_t ly = f2bf_u(kv.y - __uint_as_float(hy << 16));
    uint32_t lz = f2bf_u(kv.z - __uint_as_float(hz << 16));
    uint32_t lw = f2bf_u(kv.w - __uint_as_float(hw << 16));
    int phys = row * 64 + (((d0 >> 3) ^ (row & 7)) << 3) + (d0 & 7);
    *(ushort4*)(Khg + tb + phys) =
        make_ushort4((unsigned short)hx, (unsigned short)hy, (unsigned short)hz, (unsigned short)hw);
    *(ushort4*)(Klg + tb + phys) =
        make_ushort4((unsigned short)lx, (unsigned short)ly, (unsigned short)lz, (unsigned short)lw);
    float4 vv = *(const float4*)(v + src + row * Dc + d0);  // DVc == Dc
    *(float4*)(&Vs[row * 65 + d0]) = vv;
  }
  __syncthreads();
  const int dv = t >> 2;
  const int j0 = (t & 3) << 1;  // two sk-chunks per thread
#pragma unroll
  for (int g = 0; g < 2; ++g) {
    int chunk = j0 + g;
    unsigned short tmp[8];
#pragma unroll
    for (int s = 0; s < 8; ++s)
      tmp[s] = (unsigned short)f2bf_u(Vs[(chunk * 8 + s) * 65 + dv]);
    *(short8*)(Vtg + tb + dv * 64 + ((chunk ^ (dv & 7)) << 3)) = *(const short8*)tmp;
  }
}

__global__ __launch_bounds__(512, 4) void attn_main(
    const float* __restrict__ q, const unsigned short* __restrict__ Khg,
    const unsigned short* __restrict__ Klg, const unsigned short* __restrict__ Vtg,
    const unsigned long long* __restrict__ Mg, float* __restrict__ out) {
  // double-buffered staging: each buffer Kh [0,4096) Kl [4096,8192) Vt [8192,12288)
  // shorts; 24 KB x2 = 48 KB. 8 waves all consume the same tile.
  __shared__ __align__(16) unsigned short stag[2][12288];

  const int t = threadIdx.x;
  const int lane = t & 63;
  const int w = t >> 6;        // 8 waves = 8 q-row groups of 16
  const int lm = lane & 15;
  const int quad = lane >> 4;

  // XCD swizzle: 64 consecutive vids (4 heads) per XCD -> K/V tiles L2-resident
  const int vid = (blockIdx.x & 7) * 64 + (blockIdx.x >> 3);
  const int qt = vid & 15;            // 16 q-tiles of 128 rows
  const int h = (vid >> 4) & 15;
  const int b = vid >> 8;
  const int qrow = qt * 128 + w * 16 + lm;
  const uint32_t mrow = (uint32_t)((b * Hh + h) * SQc + qrow);  // global flat row

  // ---- Q B-frags (fp32 * log2e -> split bf16 in regs), constant over k-loop ----
  short8 qh[2], ql[2];
  {
    const float* qp = q + (((size_t)(b * Hh + h)) * SQc + qrow) * Dc;
#pragma unroll
    for (int c = 0; c < 2; ++c) {
#pragma unroll
      for (int j2 = 0; j2 < 2; ++j2) {
        float4 x = *(const float4*)(qp + c * 32 + quad * 8 + j2 * 4);
        float xs[4] = {x.x * LOG2E, x.y * LOG2E, x.z * LOG2E, x.w * LOG2E};
#pragma unroll
        for (int j = 0; j < 4; ++j) {
          uint32_t hb = f2bf_u(xs[j]);
          float lo = xs[j] - __uint_as_float(hb << 16);
          qh[c][j2 * 4 + j] = (short)hb;
          ql[c][j2 * 4 + j] = (short)f2bf_u(lo);
        }
      }
    }
  }

  const char* kh_t = (const char*)Khg + (size_t)(h * 32) * 8192;
  const char* kl_t = (const char*)Klg + (size_t)(h * 32) * 8192;
  const char* vt_t = (const char*)Vtg + (size_t)(h * 32) * 8192;

  f32x4 acc[4] = {{0.f, 0.f, 0.f, 0.f}, {0.f, 0.f, 0.f, 0.f},
                  {0.f, 0.f, 0.f, 0.f}, {0.f, 0.f, 0.f, 0.f}};
  float l_i = 0.f;  // fixed-m (m=0) partial denominator

  // swizzled LDS read offsets (shorts), loop-invariant
  const int e = lm & 7;
  const int a0s = lm * 64 + ((quad ^ e) << 3);        // chunks 0..3
  const int a1s = lm * 64 + (((quad + 4) ^ e) << 3);  // chunks 4..7

  // bpermute byte-addresses for the cross-quad P exchange (constant per lane)
  const int pa0 = ((quad & 1) * 32 + lm) << 2;
  const int pa1 = pa0 + 64;
  const uint32_t sel = (quad >= 2) ? 0x07060302u : 0x05040100u;

  // staging offset for this wave (3 KB of the 24 KB tile)
  const int soff = w * 1024 + lane * 16;

  // ---- prologue: stage tile 0 into stag[0] ----
  {
    char* db = (char*)&stag[0][0];
    gl_lds16(kh_t + soff, db + soff);
    gl_lds16(kl_t + soff, db + 8192 + soff);
    gl_lds16(vt_t + soff, db + 16384 + soff);
  }

#pragma unroll 1
  for (int i = 0; i < 32; ++i) {
    // mask word for (row, tile i): lo = k-chunk 0, hi = k-chunk 1 (bit quad*4+r, +16)
    const uint2 mw = *(const uint2*)&Mg[(size_t)mrow * 32 + i];
    // barrier: (a) drains this wave's staging issued last iter (tile i ready),
    // (b) all waves done reading the buffer tile i+1 will overwrite.
    __syncthreads();
    // ---- issue next tile's staging into the other buffer (drained NEXT iter) ----
    if (i < 31) {
      const size_t tile = (size_t)(i + 1) * 8192;
      char* db = (char*)&stag[(i & 1) ^ 1][0];
      gl_lds16(kh_t + tile + soff, db + soff);
      gl_lds16(kl_t + tile + soff, db + 8192 + soff);
      gl_lds16(vt_t + tile + soff, db + 16384 + soff);
    }
    const unsigned short* sb = &stag[i & 1][0];

#pragma unroll
    for (int c = 0; c < 2; ++c) {
      // ---- S^T for K-rows of chunk c : 3-term split bf16 ----
      f32x4 s0 = {0.f, 0.f, 0.f, 0.f}, s1 = {0.f, 0.f, 0.f, 0.f};
#pragma unroll
      for (int d = 0; d < 2; ++d) {
        const int ad = (d == 0) ? a0s : a1s;
        short8 kh0 = *(const short8*)&sb[ad + (2 * c) * 1024];
        short8 kl0 = *(const short8*)&sb[ad + (2 * c) * 1024 + 4096];
        s0 = __builtin_amdgcn_mfma_f32_16x16x32_bf16(kh0, qh[d], s0, 0, 0, 0);
        s0 = __builtin_amdgcn_mfma_f32_16x16x32_bf16(kl0, qh[d], s0, 0, 0, 0);
        s0 = __builtin_amdgcn_mfma_f32_16x16x32_bf16(kh0, ql[d], s0, 0, 0, 0);
        short8 kh1 = *(const short8*)&sb[ad + (2 * c + 1) * 1024];
        short8 kl1 = *(const short8*)&sb[ad + (2 * c + 1) * 1024 + 4096];
        s1 = __builtin_amdgcn_mfma_f32_16x16x32_bf16(kh1, qh[d], s1, 0, 0, 0);
        s1 = __builtin_amdgcn_mfma_f32_16x16x32_bf16(kl1, qh[d], s1, 0, 0, 0);
        s1 = __builtin_amdgcn_mfma_f32_16x16x32_bf16(kh1, ql[d], s1, 0, 0, 0);
      }

      // ---- p = exp2(s) (Q pre-scaled by log2e; fixed m, fp32-safe);
      //      dropout from precomputed mask bits; HW pack v_cvt_pk_bf16_f32 ----
      const uint32_t ms = ((c == 0) ? mw.x : mw.y) >> (quad * 4);
      uint32_t pkc[4];
#pragma unroll
      for (int r = 0; r < 4; ++r) {
        float p0 = __builtin_amdgcn_exp2f(s0[r]);
        float p1 = __builtin_amdgcn_exp2f(s1[r]);
        l_i += p0 + p1;  // denominator over UNdropped probs
        float k0 = (ms & (1u << r)) ? p0 : 0.0f;
        float k1 = (ms & (1u << (r + 16))) ? p1 : 0.0f;
        uint32_t pk;
        asm("v_cvt_pk_bf16_f32 %0, %1, %2" : "=v"(pk) : "v"(k0), "v"(k1));
        pkc[r] = pk;  // (bf16(k1)<<16)|bf16(k0), RNE
      }

      // ---- P^T B-frag via cross-quad bpermute (no barrier) ----
      short8 pb;
      {
        uint32_t e0 = (uint32_t)__builtin_amdgcn_ds_bpermute(pa0, (int)pkc[0]);
        uint32_t e1 = (uint32_t)__builtin_amdgcn_ds_bpermute(pa0, (int)pkc[1]);
        uint32_t e2 = (uint32_t)__builtin_amdgcn_ds_bpermute(pa0, (int)pkc[2]);
        uint32_t e3 = (uint32_t)__builtin_amdgcn_ds_bpermute(pa0, (int)pkc[3]);
        uint32_t f0 = (uint32_t)__builtin_amdgcn_ds_bpermute(pa1, (int)pkc[0]);
        uint32_t f1 = (uint32_t)__builtin_amdgcn_ds_bpermute(pa1, (int)pkc[1]);
        uint32_t f2 = (uint32_t)__builtin_amdgcn_ds_bpermute(pa1, (int)pkc[2]);
        uint32_t f3 = (uint32_t)__builtin_amdgcn_ds_bpermute(pa1, (int)pkc[3]);
        uint32_t w0 = __builtin_amdgcn_perm(e1, e0, sel);
        uint32_t w1 = __builtin_amdgcn_perm(e3, e2, sel);
        uint32_t w2 = __builtin_amdgcn_perm(f1, f0, sel);
        uint32_t w3 = __builtin_amdgcn_perm(f3, f2, sel);
        uint32_t tmp[4] = {w0, w1, w2, w3};
        pb = *(const short8*)tmp;  // B[k=quad*8+j][n=lm] for sk-chunk c
      }

      // ---- O^T += V^T(chunk c) . P^T(chunk c), V^T frags from LDS ----
      {
        const int ac = (c == 0) ? a0s : a1s;
#pragma unroll
        for (int nb = 0; nb < 4; ++nb) {
          short8 vb = *(const short8*)&sb[ac + nb * 1024 + 8192];
          acc[nb] = __builtin_amdgcn_mfma_f32_16x16x32_bf16(vb, pb, acc[nb], 0, 0, 0);
        }
      }
    }
  }

  // ---- each wave owns its q-rows completely: reduce l across quads, write out ----
  l_i += __shfl_xor(l_i, 16);
  l_i += __shfl_xor(l_i, 32);
  const float sc = (0.5f / 0.9f) / l_i;
  float* op = out + (((size_t)(b * Hh + h)) * SQc + qrow) * DVc;
#pragma unroll
  for (int nb = 0; nb < 4; ++nb) {
    float4 o = make_float4(acc[nb][0] * sc, acc[nb][1] * sc,
                           acc[nb][2] * sc, acc[nb][3] * sc);
    *(float4*)(op + nb * 16 + quad * 4) = o;
  }
}

extern "C" void kernel_launch(void* const* d_in, const int* in_sizes, int n_in,
                              void* d_out, int out_size, void* d_ws, size_t ws_size,
                              hipStream_t stream) {
  const float* q = (const float*)d_in[0];
  const float* k = (const float*)d_in[1];
  const float* v = (const float*)d_in[2];
  float* out = (float*)d_out;
  // ws layout: Kh (4 MB) | Kl (4 MB) | Vt (4 MB) | mask (16 MB) = 28 MB
  unsigned short* Khg = (unsigned short*)d_ws;
  unsigned short* Klg = Khg + (size_t)Hh * SKc * Dc;
  unsigned short* Vtg = Klg + (size_t)Hh * SKc * Dc;
  unsigned long long* Mg = (unsigned long long*)(Vtg + (size_t)Hh * SKc * Dc);
  prep_kernel<<<dim3(Hh * 32), 256, 0, stream>>>(k, v, Khg, Klg, Vtg);
  mask_kernel<<<dim3(2048), 256, 0, stream>>>(Mg);
  attn_main<<<dim3(Bb * Hh * (SQc / 128)), 512, 0, stream>>>(q, Khg, Klg, Vtg, Mg, out);
}

// Round 7
// 386.459 us; speedup vs baseline: 1.1946x; 1.1946x over previous
//
#include <hip/hip_runtime.h>
#include <stdint.h>
#include <math.h>

// (B,H,SQ,SK,D,DV) = (2,16,2048,2048,64,64)
// out = (softmax(q k^T) * 0.5) with dropout p=0.1 (jax x64 threefry key 42) @ v
// R17: mask_kernel ILP restructure. R16 split validated (attn ~100us) but mask
// ran 351us vs ~123us issue-ideal: one serial threefry chain per wave (VGPR=4),
// per-word __ballot + divergent lane-0 store. Now each LANE builds its own
// 64-bit mask word: 64 independent tf calls per lane, manual 4-way unroll ->
// 4 concurrent chains/lane, no ballot, coalesced dwordx2 stores (512B/wave).
// Same total threefry work (2^27 calls). attn_main/prep unchanged from R16.
// Mask convention (verified bit-exact R13): bits64(i) = (o0<<32)|o1 of
// threefry((0,42),(0,i)); keep iff bits64 < 0xE666666666667000 (0.9_f64).
// ws: Kh (4MB) | Kl (4MB) | Vt (4MB) | mask (16MB) = 28 MB.
namespace {
constexpr int Bb = 2, Hh = 16, SQc = 2048, SKc = 2048, Dc = 64, DVc = 64;
constexpr int TK = 64;
constexpr float LOG2E = 1.4426950408889634f;
constexpr uint64_t KEEP_T = 0xE666666666667000ull;  // 0.9_f64 threshold, exact

typedef __attribute__((ext_vector_type(8))) short short8;   // MFMA A/B frag (8 bf16)
typedef __attribute__((ext_vector_type(4))) float f32x4;    // MFMA C/D frag

__device__ __forceinline__ uint32_t rotl_(uint32_t x, int r) {
  return __builtin_amdgcn_alignbit(x, x, 32 - r);  // 1-instr rotate
}

// threefry2x32, key=(0,42), counter=(0, i): returns (o0 << 32) | o1.
// Injection adds fused with the following round's x0-add (v_add3_u32); mod-2^32
// associativity keeps it bit-exact vs the textbook form. VERIFIED R13.
__device__ __forceinline__ uint64_t tf_bits64(uint32_t ctr) {
  const uint32_t KS1 = 42u, KS2 = 0x1BD11BF0u;  // 0x1BD11BDA ^ 42
  uint32_t x0, x1;
  x1 = ctr + KS1;
  // group 1 (rot 13,15,26,6); x0 starts at 0 so first add folds
  x0 = x1;        x1 = rotl_(x1, 13); x1 ^= x0;
  x0 += x1;       x1 = rotl_(x1, 15); x1 ^= x0;
  x0 += x1;       x1 = rotl_(x1, 26); x1 ^= x0;
  x0 += x1;       x1 = rotl_(x1,  6); x1 ^= x0;
  // inject (KS1, KS2+1), fused
  x1 += KS2 + 1u;
  x0 += KS1 + x1; x1 = rotl_(x1, 17); x1 ^= x0;
  x0 += x1;       x1 = rotl_(x1, 29); x1 ^= x0;
  x0 += x1;       x1 = rotl_(x1, 16); x1 ^= x0;
  x0 += x1;       x1 = rotl_(x1, 24); x1 ^= x0;
  // inject (KS2, 0+2), fused
  x1 += 2u;
  x0 += KS2 + x1; x1 = rotl_(x1, 13); x1 ^= x0;
  x0 += x1;       x1 = rotl_(x1, 15); x1 ^= x0;
  x0 += x1;       x1 = rotl_(x1, 26); x1 ^= x0;
  x0 += x1;       x1 = rotl_(x1,  6); x1 ^= x0;
  // inject (0, KS1+3)
  x1 += KS1 + 3u;
  x0 += x1;       x1 = rotl_(x1, 17); x1 ^= x0;
  x0 += x1;       x1 = rotl_(x1, 29); x1 ^= x0;
  x0 += x1;       x1 = rotl_(x1, 16); x1 ^= x0;
  x0 += x1;       x1 = rotl_(x1, 24); x1 ^= x0;
  // inject (KS1, KS2+4), fused
  x1 += KS2 + 4u;
  x0 += KS1 + x1; x1 = rotl_(x1, 13); x1 ^= x0;
  x0 += x1;       x1 = rotl_(x1, 15); x1 ^= x0;
  x0 += x1;       x1 = rotl_(x1, 26); x1 ^= x0;
  x0 += x1;       x1 = rotl_(x1,  6); x1 ^= x0;
  // final inject (KS2, 0+5); o0 is the HIGH word (jax 64-bit combine)
  return ((uint64_t)(x0 + KS2) << 32) | (uint64_t)(x1 + 5u);
}

__device__ __forceinline__ uint32_t f2bf_u(float x) {  // RNE bf16 (finite x), low 16 bits
  uint32_t u = __float_as_uint(x);
  u += 0x7FFFu + ((u >> 16) & 1u);
  return u >> 16;
}

// async global->LDS, 16 B per lane; LDS base wave-uniform, global addr per-lane
__device__ __forceinline__ void gl_lds16(const void* g, void* l) {
  __builtin_amdgcn_global_load_lds(
      (const __attribute__((address_space(1))) unsigned int*)g,
      (__attribute__((address_space(3))) unsigned int*)l, 16, 0, 0);
}
}  // namespace

// Dropout mask pre-pass: pure ALU. Each LANE owns word W = wave*64 + lane and
// computes its 64 bits with 64 independent threefry calls (4-way unrolled ->
// 4 concurrent dep-chains per lane). Coalesced u64 store per lane.
// 32768 waves = 8192 blocks x 4.
__global__ __launch_bounds__(256, 8) void mask_kernel(
    unsigned long long* __restrict__ Mg) {
  const int lane = threadIdx.x & 63;
  const uint32_t wv = blockIdx.x * 4u + (threadIdx.x >> 6);
  const uint32_t W = wv * 64u + (uint32_t)lane;   // this lane's mask word
  const uint32_t cb = W * 64u;                     // element base for bit 0
  uint32_t lo = 0u, hi = 0u;
#pragma unroll 1
  for (int j = 0; j < 64; j += 4) {
    // 4 independent chains
    uint64_t b0 = tf_bits64(cb + (uint32_t)j);
    uint64_t b1 = tf_bits64(cb + (uint32_t)j + 1u);
    uint64_t b2 = tf_bits64(cb + (uint32_t)j + 2u);
    uint64_t b3 = tf_bits64(cb + (uint32_t)j + 3u);
    uint32_t m = (b0 < KEEP_T ? 1u : 0u) | (b1 < KEEP_T ? 2u : 0u) |
                 (b2 < KEEP_T ? 4u : 0u) | (b3 < KEEP_T ? 8u : 0u);
    if (j < 32) lo |= m << j; else hi |= m << (j - 32);
  }
  Mg[W] = ((unsigned long long)hi << 32) | lo;
}

// Pre-pass: tile-contiguous, XOR-swizzled layouts.
// Kh/Kl tile (h,kt): shorts[4096]; elem (row,col): row*64 + ((col>>3)^(row&7))*8 + (col&7)
// Vt tile  (h,kt): shorts[4096]; elem (dv,skl) = V[kt*64+skl][dv], same swizzle on skl.
__global__ __launch_bounds__(256) void prep_kernel(
    const float* __restrict__ k, const float* __restrict__ v,
    unsigned short* __restrict__ Khg, unsigned short* __restrict__ Klg,
    unsigned short* __restrict__ Vtg) {
  __shared__ float Vs[64 * 65];
  const int t = threadIdx.x;
  const int h = blockIdx.x >> 5;
  const int kt = blockIdx.x & 31;
  const size_t src = ((size_t)h * SKc + kt * 64) * Dc;
  const size_t tb = (size_t)(h * 32 + kt) * 4096;  // tile base (shorts)
#pragma unroll
  for (int i = 0; i < 4; ++i) {
    int idx = t + 256 * i;
    int row = idx >> 4, d0 = (idx & 15) << 2;
    float4 kv = *(const float4*)(k + src + row * Dc + d0);
    uint32_t hx = f2bf_u(kv.x), hy = f2bf_u(kv.y), hz = f2bf_u(kv.z), hw = f2bf_u(kv.w);
    uint32_t lx = f2bf_u(kv.x - __uint_as_float(hx << 16));
    uint32_t ly = f2bf_u(kv.y - __uint_as_float(hy << 16));
    uint32_t lz = f2bf_u(kv.z - __uint_as_float(hz << 16));
    uint32_t lw = f2bf_u(kv.w - __uint_as_float(hw << 16));
    int phys = row * 64 + (((d0 >> 3) ^ (row & 7)) << 3) + (d0 & 7);
    *(ushort4*)(Khg + tb + phys) =
        make_ushort4((unsigned short)hx, (unsigned short)hy, (unsigned short)hz, (unsigned short)hw);
    *(ushort4*)(Klg + tb + phys) =
        make_ushort4((unsigned short)lx, (unsigned short)ly, (unsigned short)lz, (unsigned short)lw);
    float4 vv = *(const float4*)(v + src + row * Dc + d0);  // DVc == Dc
    *(float4*)(&Vs[row * 65 + d0]) = vv;
  }
  __syncthreads();
  const int dv = t >> 2;
  const int j0 = (t & 3) << 1;  // two sk-chunks per thread
#pragma unroll
  for (int g = 0; g < 2; ++g) {
    int chunk = j0 + g;
    unsigned short tmp[8];
#pragma unroll
    for (int s = 0; s < 8; ++s)
      tmp[s] = (unsigned short)f2bf_u(Vs[(chunk * 8 + s) * 65 + dv]);
    *(short8*)(Vtg + tb + dv * 64 + ((chunk ^ (dv & 7)) << 3)) = *(const short8*)tmp;
  }
}

__global__ __launch_bounds__(512, 4) void attn_main(
    const float* __restrict__ q, const unsigned short* __restrict__ Khg,
    const unsigned short* __restrict__ Klg, const unsigned short* __restrict__ Vtg,
    const unsigned long long* __restrict__ Mg, float* __restrict__ out) {
  // double-buffered staging: each buffer Kh [0,4096) Kl [4096,8192) Vt [8192,12288)
  // shorts; 24 KB x2 = 48 KB. 8 waves all consume the same tile.
  __shared__ __align__(16) unsigned short stag[2][12288];

  const int t = threadIdx.x;
  const int lane = t & 63;
  const int w = t >> 6;        // 8 waves = 8 q-row groups of 16
  const int lm = lane & 15;
  const int quad = lane >> 4;

  // XCD swizzle: 64 consecutive vids (4 heads) per XCD -> K/V tiles L2-resident
  const int vid = (blockIdx.x & 7) * 64 + (blockIdx.x >> 3);
  const int qt = vid & 15;            // 16 q-tiles of 128 rows
  const int h = (vid >> 4) & 15;
  const int b = vid >> 8;
  const int qrow = qt * 128 + w * 16 + lm;
  const uint32_t mrow = (uint32_t)((b * Hh + h) * SQc + qrow);  // global flat row

  // ---- Q B-frags (fp32 * log2e -> split bf16 in regs), constant over k-loop ----
  short8 qh[2], ql[2];
  {
    const float* qp = q + (((size_t)(b * Hh + h)) * SQc + qrow) * Dc;
#pragma unroll
    for (int c = 0; c < 2; ++c) {
#pragma unroll
      for (int j2 = 0; j2 < 2; ++j2) {
        float4 x = *(const float4*)(qp + c * 32 + quad * 8 + j2 * 4);
        float xs[4] = {x.x * LOG2E, x.y * LOG2E, x.z * LOG2E, x.w * LOG2E};
#pragma unroll
        for (int j = 0; j < 4; ++j) {
          uint32_t hb = f2bf_u(xs[j]);
          float lo = xs[j] - __uint_as_float(hb << 16);
          qh[c][j2 * 4 + j] = (short)hb;
          ql[c][j2 * 4 + j] = (short)f2bf_u(lo);
        }
      }
    }
  }

  const char* kh_t = (const char*)Khg + (size_t)(h * 32) * 8192;
  const char* kl_t = (const char*)Klg + (size_t)(h * 32) * 8192;
  const char* vt_t = (const char*)Vtg + (size_t)(h * 32) * 8192;

  f32x4 acc[4] = {{0.f, 0.f, 0.f, 0.f}, {0.f, 0.f, 0.f, 0.f},
                  {0.f, 0.f, 0.f, 0.f}, {0.f, 0.f, 0.f, 0.f}};
  float l_i = 0.f;  // fixed-m (m=0) partial denominator

  // swizzled LDS read offsets (shorts), loop-invariant
  const int e = lm & 7;
  const int a0s = lm * 64 + ((quad ^ e) << 3);        // chunks 0..3
  const int a1s = lm * 64 + (((quad + 4) ^ e) << 3);  // chunks 4..7

  // bpermute byte-addresses for the cross-quad P exchange (constant per lane)
  const int pa0 = ((quad & 1) * 32 + lm) << 2;
  const int pa1 = pa0 + 64;
  const uint32_t sel = (quad >= 2) ? 0x07060302u : 0x05040100u;

  // staging offset for this wave (3 KB of the 24 KB tile)
  const int soff = w * 1024 + lane * 16;

  // ---- prologue: stage tile 0 into stag[0] ----
  {
    char* db = (char*)&stag[0][0];
    gl_lds16(kh_t + soff, db + soff);
    gl_lds16(kl_t + soff, db + 8192 + soff);
    gl_lds16(vt_t + soff, db + 16384 + soff);
  }

#pragma unroll 1
  for (int i = 0; i < 32; ++i) {
    // mask word for (row, tile i): lo = k-chunk 0, hi = k-chunk 1 (bit quad*4+r, +16)
    const uint2 mw = *(const uint2*)&Mg[(size_t)mrow * 32 + i];
    // barrier: (a) drains this wave's staging issued last iter (tile i ready),
    // (b) all waves done reading the buffer tile i+1 will overwrite.
    __syncthreads();
    // ---- issue next tile's staging into the other buffer (drained NEXT iter) ----
    if (i < 31) {
      const size_t tile = (size_t)(i + 1) * 8192;
      char* db = (char*)&stag[(i & 1) ^ 1][0];
      gl_lds16(kh_t + tile + soff, db + soff);
      gl_lds16(kl_t + tile + soff, db + 8192 + soff);
      gl_lds16(vt_t + tile + soff, db + 16384 + soff);
    }
    const unsigned short* sb = &stag[i & 1][0];

#pragma unroll
    for (int c = 0; c < 2; ++c) {
      // ---- S^T for K-rows of chunk c : 3-term split bf16 ----
      f32x4 s0 = {0.f, 0.f, 0.f, 0.f}, s1 = {0.f, 0.f, 0.f, 0.f};
#pragma unroll
      for (int d = 0; d < 2; ++d) {
        const int ad = (d == 0) ? a0s : a1s;
        short8 kh0 = *(const short8*)&sb[ad + (2 * c) * 1024];
        short8 kl0 = *(const short8*)&sb[ad + (2 * c) * 1024 + 4096];
        s0 = __builtin_amdgcn_mfma_f32_16x16x32_bf16(kh0, qh[d], s0, 0, 0, 0);
        s0 = __builtin_amdgcn_mfma_f32_16x16x32_bf16(kl0, qh[d], s0, 0, 0, 0);
        s0 = __builtin_amdgcn_mfma_f32_16x16x32_bf16(kh0, ql[d], s0, 0, 0, 0);
        short8 kh1 = *(const short8*)&sb[ad + (2 * c + 1) * 1024];
        short8 kl1 = *(const short8*)&sb[ad + (2 * c + 1) * 1024 + 4096];
        s1 = __builtin_amdgcn_mfma_f32_16x16x32_bf16(kh1, qh[d], s1, 0, 0, 0);
        s1 = __builtin_amdgcn_mfma_f32_16x16x32_bf16(kl1, qh[d], s1, 0, 0, 0);
        s1 = __builtin_amdgcn_mfma_f32_16x16x32_bf16(kh1, ql[d], s1, 0, 0, 0);
      }

      // ---- p = exp2(s) (Q pre-scaled by log2e; fixed m, fp32-safe);
      //      dropout from precomputed mask bits; HW pack v_cvt_pk_bf16_f32 ----
      const uint32_t ms = ((c == 0) ? mw.x : mw.y) >> (quad * 4);
      uint32_t pkc[4];
#pragma unroll
      for (int r = 0; r < 4; ++r) {
        float p0 = __builtin_amdgcn_exp2f(s0[r]);
        float p1 = __builtin_amdgcn_exp2f(s1[r]);
        l_i += p0 + p1;  // denominator over UNdropped probs
        float k0 = (ms & (1u << r)) ? p0 : 0.0f;
        float k1 = (ms & (1u << (r + 16))) ? p1 : 0.0f;
        uint32_t pk;
        asm("v_cvt_pk_bf16_f32 %0, %1, %2" : "=v"(pk) : "v"(k0), "v"(k1));
        pkc[r] = pk;  // (bf16(k1)<<16)|bf16(k0), RNE
      }

      // ---- P^T B-frag via cross-quad bpermute (no barrier) ----
      short8 pb;
      {
        uint32_t e0 = (uint32_t)__builtin_amdgcn_ds_bpermute(pa0, (int)pkc[0]);
        uint32_t e1 = (uint32_t)__builtin_amdgcn_ds_bpermute(pa0, (int)pkc[1]);
        uint32_t e2 = (uint32_t)__builtin_amdgcn_ds_bpermute(pa0, (int)pkc[2]);
        uint32_t e3 = (uint32_t)__builtin_amdgcn_ds_bpermute(pa0, (int)pkc[3]);
        uint32_t f0 = (uint32_t)__builtin_amdgcn_ds_bpermute(pa1, (int)pkc[0]);
        uint32_t f1 = (uint32_t)__builtin_amdgcn_ds_bpermute(pa1, (int)pkc[1]);
        uint32_t f2 = (uint32_t)__builtin_amdgcn_ds_bpermute(pa1, (int)pkc[2]);
        uint32_t f3 = (uint32_t)__builtin_amdgcn_ds_bpermute(pa1, (int)pkc[3]);
        uint32_t w0 = __builtin_amdgcn_perm(e1, e0, sel);
        uint32_t w1 = __builtin_amdgcn_perm(e3, e2, sel);
        uint32_t w2 = __builtin_amdgcn_perm(f1, f0, sel);
        uint32_t w3 = __builtin_amdgcn_perm(f3, f2, sel);
        uint32_t tmp[4] = {w0, w1, w2, w3};
        pb = *(const short8*)tmp;  // B[k=quad*8+j][n=lm] for sk-chunk c
      }

      // ---- O^T += V^T(chunk c) . P^T(chunk c), V^T frags from LDS ----
      {
        const int ac = (c == 0) ? a0s : a1s;
#pragma unroll
        for (int nb = 0; nb < 4; ++nb) {
          short8 vb = *(const short8*)&sb[ac + nb * 1024 + 8192];
          acc[nb] = __builtin_amdgcn_mfma_f32_16x16x32_bf16(vb, pb, acc[nb], 0, 0, 0);
        }
      }
    }
  }

  // ---- each wave owns its q-rows completely: reduce l across quads, write out ----
  l_i += __shfl_xor(l_i, 16);
  l_i += __shfl_xor(l_i, 32);
  const float sc = (0.5f / 0.9f) / l_i;
  float* op = out + (((size_t)(b * Hh + h)) * SQc + qrow) * DVc;
#pragma unroll
  for (int nb = 0; nb < 4; ++nb) {
    float4 o = make_float4(acc[nb][0] * sc, acc[nb][1] * sc,
                           acc[nb][2] * sc, acc[nb][3] * sc);
    *(float4*)(op + nb * 16 + quad * 4) = o;
  }
}

extern "C" void kernel_launch(void* const* d_in, const int* in_sizes, int n_in,
                              void* d_out, int out_size, void* d_ws, size_t ws_size,
                              hipStream_t stream) {
  const float* q = (const float*)d_in[0];
  const float* k = (const float*)d_in[1];
  const float* v = (const float*)d_in[2];
  float* out = (float*)d_out;
  // ws layout: Kh (4 MB) | Kl (4 MB) | Vt (4 MB) | mask (16 MB) = 28 MB
  unsigned short* Khg = (unsigned short*)d_ws;
  unsigned short* Klg = Khg + (size_t)Hh * SKc * Dc;
  unsigned short* Vtg = Klg + (size_t)Hh * SKc * Dc;
  unsigned long long* Mg = (unsigned long long*)(Vtg + (size_t)Hh * SKc * Dc);
  prep_kernel<<<dim3(Hh * 32), 256, 0, stream>>>(k, v, Khg, Klg, Vtg);
  mask_kernel<<<dim3(8192), 256, 0, stream>>>(Mg);
  attn_main<<<dim3(Bb * Hh * (SQc / 128)), 512, 0, stream>>>(q, Khg, Klg, Vtg, Mg, out);
}

// Round 8
// 369.855 us; speedup vs baseline: 1.2483x; 1.0449x over previous
//
#include <hip/hip_runtime.h>
#include <stdint.h>
#include <math.h>

// (B,H,SQ,SK,D,DV) = (2,16,2048,2048,64,64)
// out = (softmax(q k^T) * 0.5) with dropout p=0.1 (jax x64 threefry key 42) @ v
// R18: FUSED again (R15 base) + threefry software-pipelined one k-tile ahead.
// R17 established: int VALU issues at ~4.4 cyc/instr/wave on gfx950 (FP32 FMA's
// 2-cyc SIMD-32 pipe does NOT cover int ALU) -> threefry is an irreducible
// ~235us of VALU-issue. Split (mask 262 + attn 112 serial = 386) loses to fused
// (floor max(VALU ~250, DS/MFMA ~100)). R15 fused = 325 = 78% of floor; the gap
// includes the per-iter softmax tail waiting on the SAME iter's 1088-instr tf
// chain. Fix: compute tile i+1's 16 keep-bits into 2 u32 regs during tile i's
// compute; softmax consumes last iter's bits -> tf burst is fully independent,
// schedulable into ds-wait/MFMA/barrier-drain shadows.
// Mask convention (verified bit-exact R13): bits64(i) = (o0<<32)|o1 of
// threefry((0,42),(0,i)), i = global flat (b,h,q,k); keep iff
// bits64 < 0xE666666666667000 (exact u64 form of uniform_f64 < 0.9).
// ws: Kh (4MB) | Kl (4MB) | Vt (4MB) = 12 MB.
namespace {
constexpr int Bb = 2, Hh = 16, SQc = 2048, SKc = 2048, Dc = 64, DVc = 64;
constexpr int TK = 64;
constexpr float LOG2E = 1.4426950408889634f;
constexpr uint64_t KEEP_T = 0xE666666666667000ull;  // 0.9_f64 threshold, exact

typedef __attribute__((ext_vector_type(8))) short short8;   // MFMA A/B frag (8 bf16)
typedef __attribute__((ext_vector_type(4))) float f32x4;    // MFMA C/D frag

__device__ __forceinline__ uint32_t rotl_(uint32_t x, int r) {
  return __builtin_amdgcn_alignbit(x, x, 32 - r);  // 1-instr rotate
}

// threefry2x32, key=(0,42), counter=(0, i): returns (o0 << 32) | o1.
// Injection adds fused with the following round's x0-add (v_add3_u32); mod-2^32
// associativity keeps it bit-exact vs the textbook form. VERIFIED R13.
__device__ __forceinline__ uint64_t tf_bits64(uint32_t ctr) {
  const uint32_t KS1 = 42u, KS2 = 0x1BD11BF0u;  // 0x1BD11BDA ^ 42
  uint32_t x0, x1;
  x1 = ctr + KS1;
  // group 1 (rot 13,15,26,6); x0 starts at 0 so first add folds
  x0 = x1;        x1 = rotl_(x1, 13); x1 ^= x0;
  x0 += x1;       x1 = rotl_(x1, 15); x1 ^= x0;
  x0 += x1;       x1 = rotl_(x1, 26); x1 ^= x0;
  x0 += x1;       x1 = rotl_(x1,  6); x1 ^= x0;
  // inject (KS1, KS2+1), fused
  x1 += KS2 + 1u;
  x0 += KS1 + x1; x1 = rotl_(x1, 17); x1 ^= x0;
  x0 += x1;       x1 = rotl_(x1, 29); x1 ^= x0;
  x0 += x1;       x1 = rotl_(x1, 16); x1 ^= x0;
  x0 += x1;       x1 = rotl_(x1, 24); x1 ^= x0;
  // inject (KS2, 0+2), fused
  x1 += 2u;
  x0 += KS2 + x1; x1 = rotl_(x1, 13); x1 ^= x0;
  x0 += x1;       x1 = rotl_(x1, 15); x1 ^= x0;
  x0 += x1;       x1 = rotl_(x1, 26); x1 ^= x0;
  x0 += x1;       x1 = rotl_(x1,  6); x1 ^= x0;
  // inject (0, KS1+3)
  x1 += KS1 + 3u;
  x0 += x1;       x1 = rotl_(x1, 17); x1 ^= x0;
  x0 += x1;       x1 = rotl_(x1, 29); x1 ^= x0;
  x0 += x1;       x1 = rotl_(x1, 16); x1 ^= x0;
  x0 += x1;       x1 = rotl_(x1, 24); x1 ^= x0;
  // inject (KS1, KS2+4), fused
  x1 += KS2 + 4u;
  x0 += KS1 + x1; x1 = rotl_(x1, 13); x1 ^= x0;
  x0 += x1;       x1 = rotl_(x1, 15); x1 ^= x0;
  x0 += x1;       x1 = rotl_(x1, 26); x1 ^= x0;
  x0 += x1;       x1 = rotl_(x1,  6); x1 ^= x0;
  // final inject (KS2, 0+5); o0 is the HIGH word (jax 64-bit combine)
  return ((uint64_t)(x0 + KS2) << 32) | (uint64_t)(x1 + 5u);
}

// 16 keep-bits for one k-tile (this lane's elements): bits r / 16+r of m0 (c=0)
// and m1 (c=1), element counter = cb + c*32 + {r, 16+r}. Pure ALU, independent.
__device__ __forceinline__ void tf_block16(uint32_t cb, uint32_t& m0, uint32_t& m1) {
  uint32_t acc0 = 0u, acc1 = 0u;
#pragma unroll
  for (int r = 0; r < 4; ++r) {
    uint64_t a0 = tf_bits64(cb + (uint32_t)r);
    uint64_t a1 = tf_bits64(cb + (uint32_t)(16 + r));
    uint64_t b0 = tf_bits64(cb + (uint32_t)(32 + r));
    uint64_t b1 = tf_bits64(cb + (uint32_t)(48 + r));
    acc0 |= (a0 < KEEP_T ? (1u << r) : 0u) | (a1 < KEEP_T ? (1u << (16 + r)) : 0u);
    acc1 |= (b0 < KEEP_T ? (1u << r) : 0u) | (b1 < KEEP_T ? (1u << (16 + r)) : 0u);
  }
  m0 = acc0;
  m1 = acc1;
}

__device__ __forceinline__ uint32_t f2bf_u(float x) {  // RNE bf16 (finite x), low 16 bits
  uint32_t u = __float_as_uint(x);
  u += 0x7FFFu + ((u >> 16) & 1u);
  return u >> 16;
}

// async global->LDS, 16 B per lane; LDS base wave-uniform, global addr per-lane
__device__ __forceinline__ void gl_lds16(const void* g, void* l) {
  __builtin_amdgcn_global_load_lds(
      (const __attribute__((address_space(1))) unsigned int*)g,
      (__attribute__((address_space(3))) unsigned int*)l, 16, 0, 0);
}
}  // namespace

// Pre-pass: tile-contiguous, XOR-swizzled layouts.
// Kh/Kl tile (h,kt): shorts[4096]; elem (row,col): row*64 + ((col>>3)^(row&7))*8 + (col&7)
// Vt tile  (h,kt): shorts[4096]; elem (dv,skl) = V[kt*64+skl][dv], same swizzle on skl.
__global__ __launch_bounds__(256) void prep_kernel(
    const float* __restrict__ k, const float* __restrict__ v,
    unsigned short* __restrict__ Khg, unsigned short* __restrict__ Klg,
    unsigned short* __restrict__ Vtg) {
  __shared__ float Vs[64 * 65];
  const int t = threadIdx.x;
  const int h = blockIdx.x >> 5;
  const int kt = blockIdx.x & 31;
  const size_t src = ((size_t)h * SKc + kt * 64) * Dc;
  const size_t tb = (size_t)(h * 32 + kt) * 4096;  // tile base (shorts)
#pragma unroll
  for (int i = 0; i < 4; ++i) {
    int idx = t + 256 * i;
    int row = idx >> 4, d0 = (idx & 15) << 2;
    float4 kv = *(const float4*)(k + src + row * Dc + d0);
    uint32_t hx = f2bf_u(kv.x), hy = f2bf_u(kv.y), hz = f2bf_u(kv.z), hw = f2bf_u(kv.w);
    uint32_t lx = f2bf_u(kv.x - __uint_as_float(hx << 16));
    uint32_t ly = f2bf_u(kv.y - __uint_as_float(hy << 16));
    uint32_t lz = f2bf_u(kv.z - __uint_as_float(hz << 16));
    uint32_t lw = f2bf_u(kv.w - __uint_as_float(hw << 16));
    int phys = row * 64 + (((d0 >> 3) ^ (row & 7)) << 3) + (d0 & 7);
    *(ushort4*)(Khg + tb + phys) =
        make_ushort4((unsigned short)hx, (unsigned short)hy, (unsigned short)hz, (unsigned short)hw);
    *(ushort4*)(Klg + tb + phys) =
        make_ushort4((unsigned short)lx, (unsigned short)ly, (unsigned short)lz, (unsigned short)lw);
    float4 vv = *(const float4*)(v + src + row * Dc + d0);  // DVc == Dc
    *(float4*)(&Vs[row * 65 + d0]) = vv;
  }
  __syncthreads();
  const int dv = t >> 2;
  const int j0 = (t & 3) << 1;  // two sk-chunks per thread
#pragma unroll
  for (int g = 0; g < 2; ++g) {
    int chunk = j0 + g;
    unsigned short tmp[8];
#pragma unroll
    for (int s = 0; s < 8; ++s)
      tmp[s] = (unsigned short)f2bf_u(Vs[(chunk * 8 + s) * 65 + dv]);
    *(short8*)(Vtg + tb + dv * 64 + ((chunk ^ (dv & 7)) << 3)) = *(const short8*)tmp;
  }
}

__global__ __launch_bounds__(512, 4) void attn_main(
    const float* __restrict__ q, const unsigned short* __restrict__ Khg,
    const unsigned short* __restrict__ Klg, const unsigned short* __restrict__ Vtg,
    float* __restrict__ out) {
  // double-buffered staging: each buffer Kh [0,4096) Kl [4096,8192) Vt [8192,12288)
  // shorts; 24 KB x2 = 48 KB. 8 waves all consume the same tile.
  __shared__ __align__(16) unsigned short stag[2][12288];

  const int t = threadIdx.x;
  const int lane = t & 63;
  const int w = t >> 6;        // 8 waves = 8 q-row groups of 16
  const int lm = lane & 15;
  const int quad = lane >> 4;

  // XCD swizzle: 64 consecutive vids (4 heads) per XCD -> K/V tiles L2-resident
  const int vid = (blockIdx.x & 7) * 64 + (blockIdx.x >> 3);
  const int qt = vid & 15;            // 16 q-tiles of 128 rows
  const int h = (vid >> 4) & 15;
  const int b = vid >> 8;
  const int qrow = qt * 128 + w * 16 + lm;

  // ---- Q B-frags (fp32 * log2e -> split bf16 in regs), constant over k-loop ----
  short8 qh[2], ql[2];
  {
    const float* qp = q + (((size_t)(b * Hh + h)) * SQc + qrow) * Dc;
#pragma unroll
    for (int c = 0; c < 2; ++c) {
#pragma unroll
      for (int j2 = 0; j2 < 2; ++j2) {
        float4 x = *(const float4*)(qp + c * 32 + quad * 8 + j2 * 4);
        float xs[4] = {x.x * LOG2E, x.y * LOG2E, x.z * LOG2E, x.w * LOG2E};
#pragma unroll
        for (int j = 0; j < 4; ++j) {
          uint32_t hb = f2bf_u(xs[j]);
          float lo = xs[j] - __uint_as_float(hb << 16);
          qh[c][j2 * 4 + j] = (short)hb;
          ql[c][j2 * 4 + j] = (short)f2bf_u(lo);
        }
      }
    }
  }

  const char* kh_t = (const char*)Khg + (size_t)(h * 32) * 8192;
  const char* kl_t = (const char*)Klg + (size_t)(h * 32) * 8192;
  const char* vt_t = (const char*)Vtg + (size_t)(h * 32) * 8192;

  f32x4 acc[4] = {{0.f, 0.f, 0.f, 0.f}, {0.f, 0.f, 0.f, 0.f},
                  {0.f, 0.f, 0.f, 0.f}, {0.f, 0.f, 0.f, 0.f}};
  float l_i = 0.f;  // fixed-m (m=0) partial denominator

  // swizzled LDS read offsets (shorts), loop-invariant
  const int e = lm & 7;
  const int a0s = lm * 64 + ((quad ^ e) << 3);        // chunks 0..3
  const int a1s = lm * 64 + (((quad + 4) ^ e) << 3);  // chunks 4..7

  // bpermute byte-addresses for the cross-quad P exchange (constant per lane)
  const int pa0 = ((quad & 1) * 32 + lm) << 2;
  const int pa1 = pa0 + 64;
  const uint32_t sel = (quad >= 2) ? 0x07060302u : 0x05040100u;

  // GLOBAL flat (b,h,q,k) element index base for this lane (counter (0, i))
  uint32_t ctile = ((uint32_t)((b * Hh + h) * SQc + qrow)) * (uint32_t)SKc +
                   (uint32_t)(quad * 4);

  // staging offset for this wave (3 KB of the 24 KB tile)
  const int soff = w * 1024 + lane * 16;

  // ---- prologue: stage tile 0; compute tile 0's keep-bits ----
  {
    char* db = (char*)&stag[0][0];
    gl_lds16(kh_t + soff, db + soff);
    gl_lds16(kl_t + soff, db + 8192 + soff);
    gl_lds16(vt_t + soff, db + 16384 + soff);
  }
  uint32_t mc0, mc1;  // current tile keep-bits (c=0 / c=1)
  tf_block16(ctile, mc0, mc1);

#pragma unroll 1
  for (int i = 0; i < 32; ++i, ctile += TK) {
    // barrier: (a) drains this wave's staging issued last iter (tile i ready),
    // (b) all waves done reading the buffer tile i+1 will overwrite.
    __syncthreads();
    // ---- issue next tile's staging into the other buffer (drained NEXT iter) ----
    if (i < 31) {
      const size_t tile = (size_t)(i + 1) * 8192;
      char* db = (char*)&stag[(i & 1) ^ 1][0];
      gl_lds16(kh_t + tile + soff, db + soff);
      gl_lds16(kl_t + tile + soff, db + 8192 + soff);
      gl_lds16(vt_t + tile + soff, db + 16384 + soff);
    }
    const unsigned short* sb = &stag[i & 1][0];

    // ---- tf for NEXT tile: fully independent ALU, fills all stall shadows ----
    uint32_t mn0 = 0u, mn1 = 0u;
    if (i < 31) tf_block16(ctile + TK, mn0, mn1);

#pragma unroll
    for (int c = 0; c < 2; ++c) {
      // ---- S^T for K-rows of chunk c : 3-term split bf16 ----
      f32x4 s0 = {0.f, 0.f, 0.f, 0.f}, s1 = {0.f, 0.f, 0.f, 0.f};
#pragma unroll
      for (int d = 0; d < 2; ++d) {
        const int ad = (d == 0) ? a0s : a1s;
        short8 kh0 = *(const short8*)&sb[ad + (2 * c) * 1024];
        short8 kl0 = *(const short8*)&sb[ad + (2 * c) * 1024 + 4096];
        s0 = __builtin_amdgcn_mfma_f32_16x16x32_bf16(kh0, qh[d], s0, 0, 0, 0);
        s0 = __builtin_amdgcn_mfma_f32_16x16x32_bf16(kl0, qh[d], s0, 0, 0, 0);
        s0 = __builtin_amdgcn_mfma_f32_16x16x32_bf16(kh0, ql[d], s0, 0, 0, 0);
        short8 kh1 = *(const short8*)&sb[ad + (2 * c + 1) * 1024];
        short8 kl1 = *(const short8*)&sb[ad + (2 * c + 1) * 1024 + 4096];
        s1 = __builtin_amdgcn_mfma_f32_16x16x32_bf16(kh1, qh[d], s1, 0, 0, 0);
        s1 = __builtin_amdgcn_mfma_f32_16x16x32_bf16(kl1, qh[d], s1, 0, 0, 0);
        s1 = __builtin_amdgcn_mfma_f32_16x16x32_bf16(kh1, ql[d], s1, 0, 0, 0);
      }

      // ---- p = exp2(s) (Q pre-scaled by log2e; fixed m, fp32-safe);
      //      dropout from PIPELINED keep-bits (computed last iter, no dep on
      //      this iter's tf burst); HW pack v_cvt_pk_bf16_f32 ----
      const uint32_t ms = (c == 0) ? mc0 : mc1;
      uint32_t pkc[4];
#pragma unroll
      for (int r = 0; r < 4; ++r) {
        float p0 = __builtin_amdgcn_exp2f(s0[r]);
        float p1 = __builtin_amdgcn_exp2f(s1[r]);
        l_i += p0 + p1;  // denominator over UNdropped probs
        float k0 = (ms & (1u << r)) ? p0 : 0.0f;
        float k1 = (ms & (1u << (16 + r))) ? p1 : 0.0f;
        uint32_t pk;
        asm("v_cvt_pk_bf16_f32 %0, %1, %2" : "=v"(pk) : "v"(k0), "v"(k1));
        pkc[r] = pk;  // (bf16(k1)<<16)|bf16(k0), RNE
      }

      // ---- P^T B-frag via cross-quad bpermute (DS pipe, no barrier) ----
      short8 pb;
      {
        uint32_t e0 = (uint32_t)__builtin_amdgcn_ds_bpermute(pa0, (int)pkc[0]);
        uint32_t e1 = (uint32_t)__builtin_amdgcn_ds_bpermute(pa0, (int)pkc[1]);
        uint32_t e2 = (uint32_t)__builtin_amdgcn_ds_bpermute(pa0, (int)pkc[2]);
        uint32_t e3 = (uint32_t)__builtin_amdgcn_ds_bpermute(pa0, (int)pkc[3]);
        uint32_t f0 = (uint32_t)__builtin_amdgcn_ds_bpermute(pa1, (int)pkc[0]);
        uint32_t f1 = (uint32_t)__builtin_amdgcn_ds_bpermute(pa1, (int)pkc[1]);
        uint32_t f2 = (uint32_t)__builtin_amdgcn_ds_bpermute(pa1, (int)pkc[2]);
        uint32_t f3 = (uint32_t)__builtin_amdgcn_ds_bpermute(pa1, (int)pkc[3]);
        uint32_t w0 = __builtin_amdgcn_perm(e1, e0, sel);
        uint32_t w1 = __builtin_amdgcn_perm(e3, e2, sel);
        uint32_t w2 = __builtin_amdgcn_perm(f1, f0, sel);
        uint32_t w3 = __builtin_amdgcn_perm(f3, f2, sel);
        uint32_t tmp[4] = {w0, w1, w2, w3};
        pb = *(const short8*)tmp;  // B[k=quad*8+j][n=lm] for sk-chunk c
      }

      // ---- O^T += V^T(chunk c) . P^T(chunk c), V^T frags from LDS ----
      {
        const int ac = (c == 0) ? a0s : a1s;
#pragma unroll
        for (int nb = 0; nb < 4; ++nb) {
          short8 vb = *(const short8*)&sb[ac + nb * 1024 + 8192];
          acc[nb] = __builtin_amdgcn_mfma_f32_16x16x32_bf16(vb, pb, acc[nb], 0, 0, 0);
        }
      }
    }

    mc0 = mn0;
    mc1 = mn1;
  }

  // ---- each wave owns its q-rows completely: reduce l across quads, write out ----
  l_i += __shfl_xor(l_i, 16);
  l_i += __shfl_xor(l_i, 32);
  const float sc = (0.5f / 0.9f) / l_i;
  float* op = out + (((size_t)(b * Hh + h)) * SQc + qrow) * DVc;
#pragma unroll
  for (int nb = 0; nb < 4; ++nb) {
    float4 o = make_float4(acc[nb][0] * sc, acc[nb][1] * sc,
                           acc[nb][2] * sc, acc[nb][3] * sc);
    *(float4*)(op + nb * 16 + quad * 4) = o;
  }
}

extern "C" void kernel_launch(void* const* d_in, const int* in_sizes, int n_in,
                              void* d_out, int out_size, void* d_ws, size_t ws_size,
                              hipStream_t stream) {
  const float* q = (const float*)d_in[0];
  const float* k = (const float*)d_in[1];
  const float* v = (const float*)d_in[2];
  float* out = (float*)d_out;
  // ws layout: Kh (4 MB) | Kl (4 MB) | Vt (4 MB), tile-contiguous swizzled
  unsigned short* Khg = (unsigned short*)d_ws;
  unsigned short* Klg = Khg + (size_t)Hh * SKc * Dc;
  unsigned short* Vtg = Klg + (size_t)Hh * SKc * Dc;
  prep_kernel<<<dim3(Hh * 32), 256, 0, stream>>>(k, v, Khg, Klg, Vtg);
  attn_main<<<dim3(Bb * Hh * (SQc / 128)), 512, 0, stream>>>(q, Khg, Klg, Vtg, out);
}

// Round 9
// 365.510 us; speedup vs baseline: 1.2631x; 1.0119x over previous
//
#include <hip/hip_runtime.h>
#include <stdint.h>
#include <math.h>

// (B,H,SQ,SK,D,DV) = (2,16,2048,2048,64,64)
// out = (softmax(q k^T) * 0.5) with dropout p=0.1 (jax x64 threefry key 42) @ v
// R19: WAVE SPECIALIZATION. R17 calibration: int VALU = ~4.4 cyc/wave-instr ->
// attn's VALU-issue floor = ~265us; R15/R18 symmetric structures stuck at ~332
// (~80% issue busy) because all waves phase-lock at the barrier/DS bursts.
// Split: waves 4-7 = threefry PRODUCERS (pure ALU, never stall), write per-tile
// keep-bits to dbuf LDS mask (2x1KB); waves 0-3 = CONSUMERS (staging + MFMA +
// softmax for 32 q-rows each), read mask as broadcast u64. One barrier/tile,
// EQUAL barrier counts on both role paths. Producers keep every SIMD's issue
// port fed during consumer stalls -> target ~95% VALU busy.
// Mask convention (verified bit-exact R13): bits64(i) = (o0<<32)|o1 of
// threefry((0,42),(0,i)), i = global flat (b,h,q,k); keep iff
// bits64 < 0xE666666666667000 (exact u64 form of uniform_f64 < 0.9).
// ws: Kh (4MB) | Kl (4MB) | Vt (4MB) = 12 MB.
namespace {
constexpr int Bb = 2, Hh = 16, SQc = 2048, SKc = 2048, Dc = 64, DVc = 64;
constexpr int TK = 64;
constexpr float LOG2E = 1.4426950408889634f;
constexpr uint64_t KEEP_T = 0xE666666666667000ull;  // 0.9_f64 threshold, exact

typedef __attribute__((ext_vector_type(8))) short short8;   // MFMA A/B frag (8 bf16)
typedef __attribute__((ext_vector_type(4))) float f32x4;    // MFMA C/D frag

__device__ __forceinline__ uint32_t rotl_(uint32_t x, int r) {
  return __builtin_amdgcn_alignbit(x, x, 32 - r);  // 1-instr rotate
}

// threefry2x32, key=(0,42), counter=(0, i): returns (o0 << 32) | o1.
// Injection adds fused with the following round's x0-add (v_add3_u32); mod-2^32
// associativity keeps it bit-exact vs the textbook form. VERIFIED R13.
__device__ __forceinline__ uint64_t tf_bits64(uint32_t ctr) {
  const uint32_t KS1 = 42u, KS2 = 0x1BD11BF0u;  // 0x1BD11BDA ^ 42
  uint32_t x0, x1;
  x1 = ctr + KS1;
  // group 1 (rot 13,15,26,6); x0 starts at 0 so first add folds
  x0 = x1;        x1 = rotl_(x1, 13); x1 ^= x0;
  x0 += x1;       x1 = rotl_(x1, 15); x1 ^= x0;
  x0 += x1;       x1 = rotl_(x1, 26); x1 ^= x0;
  x0 += x1;       x1 = rotl_(x1,  6); x1 ^= x0;
  // inject (KS1, KS2+1), fused
  x1 += KS2 + 1u;
  x0 += KS1 + x1; x1 = rotl_(x1, 17); x1 ^= x0;
  x0 += x1;       x1 = rotl_(x1, 29); x1 ^= x0;
  x0 += x1;       x1 = rotl_(x1, 16); x1 ^= x0;
  x0 += x1;       x1 = rotl_(x1, 24); x1 ^= x0;
  // inject (KS2, 0+2), fused
  x1 += 2u;
  x0 += KS2 + x1; x1 = rotl_(x1, 13); x1 ^= x0;
  x0 += x1;       x1 = rotl_(x1, 15); x1 ^= x0;
  x0 += x1;       x1 = rotl_(x1, 26); x1 ^= x0;
  x0 += x1;       x1 = rotl_(x1,  6); x1 ^= x0;
  // inject (0, KS1+3)
  x1 += KS1 + 3u;
  x0 += x1;       x1 = rotl_(x1, 17); x1 ^= x0;
  x0 += x1;       x1 = rotl_(x1, 29); x1 ^= x0;
  x0 += x1;       x1 = rotl_(x1, 16); x1 ^= x0;
  x0 += x1;       x1 = rotl_(x1, 24); x1 ^= x0;
  // inject (KS1, KS2+4), fused
  x1 += KS2 + 4u;
  x0 += KS1 + x1; x1 = rotl_(x1, 13); x1 ^= x0;
  x0 += x1;       x1 = rotl_(x1, 15); x1 ^= x0;
  x0 += x1;       x1 = rotl_(x1, 26); x1 ^= x0;
  x0 += x1;       x1 = rotl_(x1,  6); x1 ^= x0;
  // final inject (KS2, 0+5); o0 is the HIGH word (jax 64-bit combine)
  return ((uint64_t)(x0 + KS2) << 32) | (uint64_t)(x1 + 5u);
}

// 32 keep-bits (k = cb+0 .. cb+31) packed into a u32, 4-way ILP.
__device__ __forceinline__ uint32_t tf_word32(uint32_t cb) {
  uint32_t m = 0u;
#pragma unroll
  for (int j = 0; j < 32; j += 4) {
    uint64_t b0 = tf_bits64(cb + (uint32_t)j);
    uint64_t b1 = tf_bits64(cb + (uint32_t)j + 1u);
    uint64_t b2 = tf_bits64(cb + (uint32_t)j + 2u);
    uint64_t b3 = tf_bits64(cb + (uint32_t)j + 3u);
    m |= (b0 < KEEP_T ? (1u << j) : 0u) | (b1 < KEEP_T ? (2u << j) : 0u) |
         (b2 < KEEP_T ? (4u << j) : 0u) | (b3 < KEEP_T ? (8u << j) : 0u);
  }
  return m;
}

__device__ __forceinline__ uint32_t f2bf_u(float x) {  // RNE bf16 (finite x), low 16 bits
  uint32_t u = __float_as_uint(x);
  u += 0x7FFFu + ((u >> 16) & 1u);
  return u >> 16;
}

// async global->LDS, 16 B per lane; LDS base wave-uniform, global addr per-lane
__device__ __forceinline__ void gl_lds16(const void* g, void* l) {
  __builtin_amdgcn_global_load_lds(
      (const __attribute__((address_space(1))) unsigned int*)g,
      (__attribute__((address_space(3))) unsigned int*)l, 16, 0, 0);
}
}  // namespace

// Pre-pass: tile-contiguous, XOR-swizzled layouts.
// Kh/Kl tile (h,kt): shorts[4096]; elem (row,col): row*64 + ((col>>3)^(row&7))*8 + (col&7)
// Vt tile  (h,kt): shorts[4096]; elem (dv,skl) = V[kt*64+skl][dv], same swizzle on skl.
__global__ __launch_bounds__(256) void prep_kernel(
    const float* __restrict__ k, const float* __restrict__ v,
    unsigned short* __restrict__ Khg, unsigned short* __restrict__ Klg,
    unsigned short* __restrict__ Vtg) {
  __shared__ float Vs[64 * 65];
  const int t = threadIdx.x;
  const int h = blockIdx.x >> 5;
  const int kt = blockIdx.x & 31;
  const size_t src = ((size_t)h * SKc + kt * 64) * Dc;
  const size_t tb = (size_t)(h * 32 + kt) * 4096;  // tile base (shorts)
#pragma unroll
  for (int i = 0; i < 4; ++i) {
    int idx = t + 256 * i;
    int row = idx >> 4, d0 = (idx & 15) << 2;
    float4 kv = *(const float4*)(k + src + row * Dc + d0);
    uint32_t hx = f2bf_u(kv.x), hy = f2bf_u(kv.y), hz = f2bf_u(kv.z), hw = f2bf_u(kv.w);
    uint32_t lx = f2bf_u(kv.x - __uint_as_float(hx << 16));
    uint32_t ly = f2bf_u(kv.y - __uint_as_float(hy << 16));
    uint32_t lz = f2bf_u(kv.z - __uint_as_float(hz << 16));
    uint32_t lw = f2bf_u(kv.w - __uint_as_float(hw << 16));
    int phys = row * 64 + (((d0 >> 3) ^ (row & 7)) << 3) + (d0 & 7);
    *(ushort4*)(Khg + tb + phys) =
        make_ushort4((unsigned short)hx, (unsigned short)hy, (unsigned short)hz, (unsigned short)hw);
    *(ushort4*)(Klg + tb + phys) =
        make_ushort4((unsigned short)lx, (unsigned short)ly, (unsigned short)lz, (unsigned short)lw);
    float4 vv = *(const float4*)(v + src + row * Dc + d0);  // DVc == Dc
    *(float4*)(&Vs[row * 65 + d0]) = vv;
  }
  __syncthreads();
  const int dv = t >> 2;
  const int j0 = (t & 3) << 1;  // two sk-chunks per thread
#pragma unroll
  for (int g = 0; g < 2; ++g) {
    int chunk = j0 + g;
    unsigned short tmp[8];
#pragma unroll
    for (int s = 0; s < 8; ++s)
      tmp[s] = (unsigned short)f2bf_u(Vs[(chunk * 8 + s) * 65 + dv]);
    *(short8*)(Vtg + tb + dv * 64 + ((chunk ^ (dv & 7)) << 3)) = *(const short8*)tmp;
  }
}

__global__ __launch_bounds__(512, 4) void attn_main(
    const float* __restrict__ q, const unsigned short* __restrict__ Khg,
    const unsigned short* __restrict__ Klg, const unsigned short* __restrict__ Vtg,
    float* __restrict__ out) {
  // staging dbuf 48KB + mask dbuf 2KB; 2 blocks/CU.
  __shared__ __align__(16) unsigned short stag[2][12288];
  __shared__ unsigned long long maskb[2][128];  // [parity][row-in-block]

  const int t = threadIdx.x;
  const int lane = t & 63;
  const int w = t >> 6;        // waves 0-3 consumers, 4-7 producers
  const int lm = lane & 15;
  const int quad = lane >> 4;

  // XCD swizzle: 64 consecutive vids (4 heads) per XCD -> K/V tiles L2-resident
  const int vid = (blockIdx.x & 7) * 64 + (blockIdx.x >> 3);
  const int qt = vid & 15;            // 16 q-tiles of 128 rows
  const int h = (vid >> 4) & 15;
  const int b = vid >> 8;

  const char* kh_t = (const char*)Khg + (size_t)(h * 32) * 8192;
  const char* kl_t = (const char*)Klg + (size_t)(h * 32) * 8192;
  const char* vt_t = (const char*)Vtg + (size_t)(h * 32) * 8192;

  if (w >= 4) {
    // ================= PRODUCER: dropout keep-bits, pure ALU =================
    // wave p covers rows p*32 + (lane&31); lane>>5 selects k-half (32 bits).
    const int p = w - 4;
    const int rp = p * 32 + (lane & 31);
    const int half = lane >> 5;
    const uint32_t grow = (uint32_t)((b * Hh + h) * SQc + qt * 128 + rp);
    const uint32_t cb0 = grow * (uint32_t)SKc + (uint32_t)(half * 32);
    uint32_t* mp0 = (uint32_t*)&maskb[0][rp] + half;
    uint32_t* mp1 = (uint32_t*)&maskb[1][rp] + half;
    *mp0 = tf_word32(cb0);  // tile 0
#pragma unroll 1
    for (int i = 0; i < 32; ++i) {
      __syncthreads();  // matches consumer barrier count exactly (32)
      if (i < 31) {
        uint32_t m = tf_word32(cb0 + (uint32_t)((i + 1) * TK));
        *(((i + 1) & 1) ? mp1 : mp0) = m;
      }
    }
    return;
  }

  // ================= CONSUMER: staging + QK^T + softmax + PV =================
  const int cw = w;                       // 0..3
  const int qb = qt * 128 + cw * 32;      // rows qb+g*16+lm, g=0,1

  // ---- Q B-frags for both q-groups (fp32 * log2e -> split bf16), loop-const ----
  short8 qh[2][2], ql[2][2];
#pragma unroll
  for (int g = 0; g < 2; ++g) {
    const float* qp = q + (((size_t)(b * Hh + h)) * SQc + qb + g * 16 + lm) * Dc;
#pragma unroll
    for (int c = 0; c < 2; ++c) {
#pragma unroll
      for (int j2 = 0; j2 < 2; ++j2) {
        float4 x = *(const float4*)(qp + c * 32 + quad * 8 + j2 * 4);
        float xs[4] = {x.x * LOG2E, x.y * LOG2E, x.z * LOG2E, x.w * LOG2E};
#pragma unroll
        for (int j = 0; j < 4; ++j) {
          uint32_t hb = f2bf_u(xs[j]);
          float lo = xs[j] - __uint_as_float(hb << 16);
          qh[g][c][j2 * 4 + j] = (short)hb;
          ql[g][c][j2 * 4 + j] = (short)f2bf_u(lo);
        }
      }
    }
  }

  f32x4 acc[2][4] = {};
  float l_i[2] = {0.f, 0.f};  // fixed-m (m=0) partial denominators

  // swizzled LDS read offsets (shorts), loop-invariant
  const int e = lm & 7;
  const int a0s = lm * 64 + ((quad ^ e) << 3);        // chunks 0..3
  const int a1s = lm * 64 + (((quad + 4) ^ e) << 3);  // chunks 4..7

  // bpermute byte-addresses for the cross-quad P exchange (constant per lane)
  const int pa0 = ((quad & 1) * 32 + lm) << 2;
  const int pa1 = pa0 + 64;
  const uint32_t sel = (quad >= 2) ? 0x07060302u : 0x05040100u;

  // staging: 4 consumer waves, 2KB slice per wave per 8KB region (2 chunks)
  const int soff = cw * 2048 + lane * 16;

  // ---- prologue: stage tile 0 ----
  {
    char* db = (char*)&stag[0][0];
    gl_lds16(kh_t + soff, db + soff);
    gl_lds16(kh_t + soff + 1024, db + soff + 1024);
    gl_lds16(kl_t + soff, db + 8192 + soff);
    gl_lds16(kl_t + soff + 1024, db + 8192 + soff + 1024);
    gl_lds16(vt_t + soff, db + 16384 + soff);
    gl_lds16(vt_t + soff + 1024, db + 16384 + soff + 1024);
  }

#pragma unroll 1
  for (int i = 0; i < 32; ++i) {
    // barrier: staging drained (tile i ready), mask[i&1] written, buffers free
    __syncthreads();
    if (i < 31) {
      const size_t tile = (size_t)(i + 1) * 8192;
      char* db = (char*)&stag[(i & 1) ^ 1][0];
      gl_lds16(kh_t + tile + soff, db + soff);
      gl_lds16(kh_t + tile + soff + 1024, db + soff + 1024);
      gl_lds16(kl_t + tile + soff, db + 8192 + soff);
      gl_lds16(kl_t + tile + soff + 1024, db + 8192 + soff + 1024);
      gl_lds16(vt_t + tile + soff, db + 16384 + soff);
      gl_lds16(vt_t + tile + soff + 1024, db + 16384 + soff + 1024);
    }
    const unsigned short* sb = &stag[i & 1][0];

#pragma unroll
    for (int g = 0; g < 2; ++g) {
      // mask word for this q-row & tile (broadcast read: all quads same lm)
      const uint64_t w64 = maskb[i & 1][cw * 32 + g * 16 + lm];

#pragma unroll
      for (int c = 0; c < 2; ++c) {
        // ---- S^T for K-rows of chunk c : 3-term split bf16 ----
        f32x4 s0 = {0.f, 0.f, 0.f, 0.f}, s1 = {0.f, 0.f, 0.f, 0.f};
#pragma unroll
        for (int d = 0; d < 2; ++d) {
          const int ad = (d == 0) ? a0s : a1s;
          short8 kh0 = *(const short8*)&sb[ad + (2 * c) * 1024];
          short8 kl0 = *(const short8*)&sb[ad + (2 * c) * 1024 + 4096];
          s0 = __builtin_amdgcn_mfma_f32_16x16x32_bf16(kh0, qh[g][d], s0, 0, 0, 0);
          s0 = __builtin_amdgcn_mfma_f32_16x16x32_bf16(kl0, qh[g][d], s0, 0, 0, 0);
          s0 = __builtin_amdgcn_mfma_f32_16x16x32_bf16(kh0, ql[g][d], s0, 0, 0, 0);
          short8 kh1 = *(const short8*)&sb[ad + (2 * c + 1) * 1024];
          short8 kl1 = *(const short8*)&sb[ad + (2 * c + 1) * 1024 + 4096];
          s1 = __builtin_amdgcn_mfma_f32_16x16x32_bf16(kh1, qh[g][d], s1, 0, 0, 0);
          s1 = __builtin_amdgcn_mfma_f32_16x16x32_bf16(kl1, qh[g][d], s1, 0, 0, 0);
          s1 = __builtin_amdgcn_mfma_f32_16x16x32_bf16(kh1, ql[g][d], s1, 0, 0, 0);
        }

        // ---- p = exp2(s); dropout from producer mask bits; cvt_pk pack ----
        const uint32_t ms = ((uint32_t)(w64 >> (c * 32))) >> (quad * 4);
        uint32_t pkc[4];
#pragma unroll
        for (int r = 0; r < 4; ++r) {
          float p0 = __builtin_amdgcn_exp2f(s0[r]);
          float p1 = __builtin_amdgcn_exp2f(s1[r]);
          l_i[g] += p0 + p1;  // denominator over UNdropped probs
          float k0 = (ms & (1u << r)) ? p0 : 0.0f;
          float k1 = (ms & (1u << (16 + r))) ? p1 : 0.0f;
          uint32_t pk;
          asm("v_cvt_pk_bf16_f32 %0, %1, %2" : "=v"(pk) : "v"(k0), "v"(k1));
          pkc[r] = pk;  // (bf16(k1)<<16)|bf16(k0), RNE
        }

        // ---- P^T B-frag via cross-quad bpermute (DS pipe, no barrier) ----
        short8 pb;
        {
          uint32_t e0 = (uint32_t)__builtin_amdgcn_ds_bpermute(pa0, (int)pkc[0]);
          uint32_t e1 = (uint32_t)__builtin_amdgcn_ds_bpermute(pa0, (int)pkc[1]);
          uint32_t e2 = (uint32_t)__builtin_amdgcn_ds_bpermute(pa0, (int)pkc[2]);
          uint32_t e3 = (uint32_t)__builtin_amdgcn_ds_bpermute(pa0, (int)pkc[3]);
          uint32_t f0 = (uint32_t)__builtin_amdgcn_ds_bpermute(pa1, (int)pkc[0]);
          uint32_t f1 = (uint32_t)__builtin_amdgcn_ds_bpermute(pa1, (int)pkc[1]);
          uint32_t f2 = (uint32_t)__builtin_amdgcn_ds_bpermute(pa1, (int)pkc[2]);
          uint32_t f3 = (uint32_t)__builtin_amdgcn_ds_bpermute(pa1, (int)pkc[3]);
          uint32_t w0 = __builtin_amdgcn_perm(e1, e0, sel);
          uint32_t w1 = __builtin_amdgcn_perm(e3, e2, sel);
          uint32_t w2 = __builtin_amdgcn_perm(f1, f0, sel);
          uint32_t w3 = __builtin_amdgcn_perm(f3, f2, sel);
          uint32_t tmp[4] = {w0, w1, w2, w3};
          pb = *(const short8*)tmp;  // B[k=quad*8+j][n=lm] for sk-chunk c
        }

        // ---- O^T += V^T(chunk c) . P^T(chunk c), V^T frags from LDS ----
        {
          const int ac = (c == 0) ? a0s : a1s;
#pragma unroll
          for (int nb = 0; nb < 4; ++nb) {
            short8 vb = *(const short8*)&sb[ac + nb * 1024 + 8192];
            acc[g][nb] = __builtin_amdgcn_mfma_f32_16x16x32_bf16(vb, pb, acc[g][nb], 0, 0, 0);
          }
        }
      }
    }
  }

  // ---- epilogue: per group, reduce l across quads, scale, store ----
#pragma unroll
  for (int g = 0; g < 2; ++g) {
    float lg = l_i[g];
    lg += __shfl_xor(lg, 16);
    lg += __shfl_xor(lg, 32);
    const float sc = (0.5f / 0.9f) / lg;
    float* op = out + (((size_t)(b * Hh + h)) * SQc + qb + g * 16 + lm) * DVc;
#pragma unroll
    for (int nb = 0; nb < 4; ++nb) {
      float4 o = make_float4(acc[g][nb][0] * sc, acc[g][nb][1] * sc,
                             acc[g][nb][2] * sc, acc[g][nb][3] * sc);
      *(float4*)(op + nb * 16 + quad * 4) = o;
    }
  }
}

extern "C" void kernel_launch(void* const* d_in, const int* in_sizes, int n_in,
                              void* d_out, int out_size, void* d_ws, size_t ws_size,
                              hipStream_t stream) {
  const float* q = (const float*)d_in[0];
  const float* k = (const float*)d_in[1];
  const float* v = (const float*)d_in[2];
  float* out = (float*)d_out;
  // ws layout: Kh (4 MB) | Kl (4 MB) | Vt (4 MB), tile-contiguous swizzled
  unsigned short* Khg = (unsigned short*)d_ws;
  unsigned short* Klg = Khg + (size_t)Hh * SKc * Dc;
  unsigned short* Vtg = Klg + (size_t)Hh * SKc * Dc;
  prep_kernel<<<dim3(Hh * 32), 256, 0, stream>>>(k, v, Khg, Klg, Vtg);
  attn_main<<<dim3(Bb * Hh * (SQc / 128)), 512, 0, stream>>>(q, Khg, Klg, Vtg, out);
}